// Round 2
// baseline (126.638 us; speedup 1.0000x reference)
//
#include <hip/hip_runtime.h>

// Problem constants (fixed by setup_inputs in the reference)
#define B_  8
#define T_  2048
#define D_  1024
#define H_  8
#define S_  128
#define DH_ 128      // D/H
#define MAXW 32      // widths in [1, 32]

// Kernel 1: logits[b*T+t][h] = sum_d feat[b,t,d]*kw[h,d] + kb[h]
// One wave per row, 4 rows per block. Lane l holds feat[row, {c*256 + 4l .. +3}]
// for c=0..3 — each wave-level float4 load covers 1 KB contiguous (perfect
// coalescing). 8 dot products -> butterfly shuffle reduce over 64 lanes.
__global__ __launch_bounds__(256) void logits_kernel(
    const float* __restrict__ feat,    // [B*T, D]
    const float* __restrict__ kw,      // [H, D]
    const float* __restrict__ kb,      // [H]
    float* __restrict__ logits)        // [B*T, H]
{
    const int wave = threadIdx.x >> 6;
    const int lane = threadIdx.x & 63;
    const int row  = blockIdx.x * 4 + wave;    // 0 .. B_*T_-1

    const float* fr = feat + (size_t)row * D_;
    float4 f[4];
#pragma unroll
    for (int c = 0; c < 4; ++c)
        f[c] = *(const float4*)(fr + c * 256 + lane * 4);

    float acc[H_];
#pragma unroll
    for (int h = 0; h < H_; ++h) {
        const float* kr = kw + h * D_;
        float s = 0.f;
#pragma unroll
        for (int c = 0; c < 4; ++c) {
            float4 k = *(const float4*)(kr + c * 256 + lane * 4);
            s += f[c].x * k.x + f[c].y * k.y + f[c].z * k.z + f[c].w * k.w;
        }
        acc[h] = s;
    }

#pragma unroll
    for (int off = 32; off >= 1; off >>= 1) {
#pragma unroll
        for (int h = 0; h < H_; ++h)
            acc[h] += __shfl_xor(acc[h], off, 64);
    }

    if (lane == 0) {
        float4 o0 = make_float4(acc[0] + kb[0], acc[1] + kb[1],
                                acc[2] + kb[2], acc[3] + kb[3]);
        float4 o1 = make_float4(acc[4] + kb[4], acc[5] + kb[5],
                                acc[6] + kb[6], acc[7] + kb[7]);
        float4* op = (float4*)(logits + (size_t)row * H_);
        op[0] = o0;
        op[1] = o1;
    }
}

// Kernel 2: one block per (b,s). NEG=-1e5 underflows to exactly 0 after exp
// (span max logit is O(1)), so full-T softmax == span-local softmax.
// Load the contiguous width*8 logit slab to LDS, 8 threads do per-head
// softmax (<=32 iters), then 256 threads each accumulate 4 output columns
// over the span with coalesced float4 loads.
__global__ __launch_bounds__(256) void pool_kernel(
    const float* __restrict__ feat,    // [B*T, D]
    const int* __restrict__ begins,    // [B*S]
    const int* __restrict__ ends,      // [B*S]
    const float* __restrict__ logits,  // [B*T, H]
    float* __restrict__ out)           // [B*S, D]
{
    const int bs  = blockIdx.x;                // 0 .. B_*S_-1
    const int b   = bs >> 7;                   // / S_
    const int tid = threadIdx.x;

    const int begin = begins[bs];
    const int end   = ends[bs];
    const int width = end - begin;             // 1..32

    __shared__ float lg[MAXW * H_];
    __shared__ float w [MAXW * H_];

    // logits slab for the span is contiguous: width*8 floats
    if (tid < width * H_)
        lg[tid] = logits[(size_t)(b * T_ + begin) * H_ + tid];
    __syncthreads();

    if (tid < H_) {
        float m = -1e30f;
        for (int i = 0; i < width; ++i) m = fmaxf(m, lg[i * H_ + tid]);
        float sum = 0.f;
        for (int i = 0; i < width; ++i) {
            float e = __expf(lg[i * H_ + tid] - m);
            w[i * H_ + tid] = e;
            sum += e;
        }
        float inv = 1.f / sum;
        for (int i = 0; i < width; ++i) w[i * H_ + tid] *= inv;
    }
    __syncthreads();

    const int col = tid * 4;                   // 0..1020
    const int hh  = tid >> 5;                  // col / DH_
    float4 acc = make_float4(0.f, 0.f, 0.f, 0.f);
    const float* fbase = feat + (size_t)(b * T_ + begin) * D_ + col;

    for (int i = 0; i < width; ++i) {
        float4 v = *(const float4*)(fbase + (size_t)i * D_);
        const float wt = w[i * H_ + hh];
        acc.x += wt * v.x;
        acc.y += wt * v.y;
        acc.z += wt * v.z;
        acc.w += wt * v.w;
    }

    *(float4*)(out + (size_t)bs * D_ + col) = acc;
}

extern "C" void kernel_launch(void* const* d_in, const int* in_sizes, int n_in,
                              void* d_out, int out_size, void* d_ws, size_t ws_size,
                              hipStream_t stream) {
    const float* feat   = (const float*)d_in[0];   // features f32 [B,T,D]
    const int*   begins = (const int*)d_in[1];     // int32 [B,S]
    const int*   ends   = (const int*)d_in[2];     // int32 [B,S]
    const float* kw     = (const float*)d_in[3];   // key_w f32 [H,D]
    const float* kb     = (const float*)d_in[4];   // key_b f32 [H]
    float*       out    = (float*)d_out;           // f32 [B*S*D]
    float* logits = (float*)d_ws;                  // 16384*8*4 = 512 KB scratch

    logits_kernel<<<(B_ * T_) / 4, 256, 0, stream>>>(feat, kw, kb, logits);
    pool_kernel<<<B_ * S_, 256, 0, stream>>>(feat, begins, ends, logits, out);
}

// Round 3
// 115.476 us; speedup vs baseline: 1.0967x; 1.0967x over previous
//
#include <hip/hip_runtime.h>

// Problem constants (fixed by setup_inputs in the reference)
#define B_  8
#define T_  2048
#define D_  1024
#define H_  8
#define S_  128

// --------------------------------------------------------------------------
// K1: logits[row][h] = dot(feat[row,:], kw[h,:]) + kb[h]   (f32)
// 8 rows per wave. For each 256-col chunk, the wave holds kw fragments for
// all 8 heads in registers (8 x float4 per lane) and streams 8 feat rows
// through them -> kw global traffic cut 8x vs one-row-per-wave (L1-resident).
// Cross-lane reduction compacts 64 partials so lane l ends with the total
// for (r = l>>3, h = l&7): 63 shuffles/wave, then one coalesced 256B store.
// --------------------------------------------------------------------------
__global__ __launch_bounds__(256) void logits_kernel(
    const float* __restrict__ feat,    // [B*T, D]
    const float* __restrict__ kw,      // [H, D]
    const float* __restrict__ kb,      // [H]
    float* __restrict__ logits)        // [B*T, H]
{
    const int wave = threadIdx.x >> 6;
    const int lane = threadIdx.x & 63;
    const int row0 = (blockIdx.x * 4 + wave) * 8;   // 512 blocks * 4 waves * 8 rows

    float acc[64];
#pragma unroll
    for (int j = 0; j < 64; ++j) acc[j] = 0.f;

#pragma unroll
    for (int c = 0; c < 4; ++c) {
        float4 kf[H_];
#pragma unroll
        for (int h = 0; h < H_; ++h)
            kf[h] = *(const float4*)(kw + h * D_ + c * 256 + lane * 4);
#pragma unroll
        for (int r = 0; r < 8; ++r) {
            float4 fv = *(const float4*)(feat + (size_t)(row0 + r) * D_ + c * 256 + lane * 4);
#pragma unroll
            for (int h = 0; h < H_; ++h)
                acc[r * 8 + h] += fv.x * kf[h].x + fv.y * kf[h].y
                                + fv.z * kf[h].z + fv.w * kf[h].w;
        }
    }

    // Value-compacting cross-lane reduce: at step s, lane bit s selects the
    // even/odd half of surviving value indices; partner halves are exchanged
    // via one shfl_xor per pair. After 6 steps acc[0] on lane l is the full
    // 64-lane sum of original value index l.  (32+16+8+4+2+1 = 63 shuffles)
#pragma unroll
    for (int s = 0; s < 6; ++s) {
        const int m = 1 << s;
        const bool hi = (lane >> s) & 1;
#pragma unroll
        for (int j = 0; j < (32 >> s); ++j) {
            float mine  = hi ? acc[2 * j + 1] : acc[2 * j];
            float other = hi ? acc[2 * j]     : acc[2 * j + 1];
            acc[j] = mine + __shfl_xor(other, m, 64);
        }
    }

    // lane l -> logits[(row0 + (l>>3)) * 8 + (l&7)] == logits[row0*8 + l]
    logits[(size_t)row0 * H_ + lane] = acc[0] + kb[lane & 7];
}

// --------------------------------------------------------------------------
// K2: barrier-free, LDS-free span softmax + weighted pool.
// One wave per (b,s,quarter-of-D). Each wave redundantly computes the whole
// span softmax in registers: lane l holds logits for t = 4l..4l+3 where
// t = i*8+h  (i = l>>1, h = 4*(l&1)+e for element e). Per-head reductions
// are parity-preserving shfl_xor over offsets {2,4,8,16,32}. Weights are
// broadcast to pooling lanes with 2 shuffles per span row. Rows i >= width
// carry weight exactly 0 (masked logit -1e30 -> exp underflows to 0), and
// rows begin..begin+31 are always in-bounds (begin <= 2015), so the pooling
// loop runs fixed unrolled 8-row chunks with no bounds checks.
// --------------------------------------------------------------------------
__global__ __launch_bounds__(256) void pool_kernel(
    const float* __restrict__ feat,    // [B*T, D]
    const int* __restrict__ begins,    // [B*S]
    const int* __restrict__ ends,      // [B*S]
    const float* __restrict__ logits,  // [B*T, H]
    float* __restrict__ out)           // [B*S, D]
{
    const int bs   = blockIdx.x;            // 0 .. B_*S_-1
    const int wv   = threadIdx.x >> 6;      // quarter of D (256 cols)
    const int lane = threadIdx.x & 63;
    const int b    = bs >> 7;               // / S_

    const int begin = begins[bs];
    const int width = ends[bs] - begin;     // 1..32
    const size_t row0 = (size_t)b * T_ + begin;

    // ---- load span logit slab (t = 4*lane .. 4*lane+3), mask t >= width*8
    float4 lv = *(const float4*)(logits + row0 * H_ + lane * 4);
    const int w8 = width * H_;
    float v0 = (4 * lane + 0 < w8) ? lv.x : -1e30f;
    float v1 = (4 * lane + 1 < w8) ? lv.y : -1e30f;
    float v2 = (4 * lane + 2 < w8) ? lv.z : -1e30f;
    float v3 = (4 * lane + 3 < w8) ? lv.w : -1e30f;

    // ---- per-head max (parity-preserving butterfly over same-parity lanes)
    float m0 = v0, m1 = v1, m2 = v2, m3 = v3;
#pragma unroll
    for (int off = 2; off <= 32; off <<= 1) {
        m0 = fmaxf(m0, __shfl_xor(m0, off, 64));
        m1 = fmaxf(m1, __shfl_xor(m1, off, 64));
        m2 = fmaxf(m2, __shfl_xor(m2, off, 64));
        m3 = fmaxf(m3, __shfl_xor(m3, off, 64));
    }

    // ---- exp + per-head sum
    float e0 = __expf(v0 - m0);             // masked -> exp(-huge) = 0
    float e1 = __expf(v1 - m1);
    float e2 = __expf(v2 - m2);
    float e3 = __expf(v3 - m3);
    float s0 = e0, s1 = e1, s2 = e2, s3 = e3;
#pragma unroll
    for (int off = 2; off <= 32; off <<= 1) {
        s0 += __shfl_xor(s0, off, 64);
        s1 += __shfl_xor(s1, off, 64);
        s2 += __shfl_xor(s2, off, 64);
        s3 += __shfl_xor(s3, off, 64);
    }
    const float w0 = e0 / s0, w1 = e1 / s1, w2 = e2 / s2, w3 = e3 / s3;

    // ---- pooling: thread covers cols [wv*256 + lane*4, +4); hh = col/128.
    // weight w[i][hh] lives on lane 2i+p, element (wv&1)*2 + (lane>=32),
    // with p = wv>>1 (wave-uniform).
    const int p = wv >> 1;
    const float wlo = (wv & 1) ? w2 : w0;
    const float whi = (wv & 1) ? w3 : w1;
    const bool hiHalf = (lane >= 32);

    const int colbase = wv * 256 + lane * 4;
    const float* fbase = feat + row0 * D_ + colbase;

    float4 acc = make_float4(0.f, 0.f, 0.f, 0.f);
    const int nch = (width + 7) >> 3;       // 1..4 chunks of 8 rows
    for (int ch = 0; ch < nch; ++ch) {
#pragma unroll
        for (int k = 0; k < 8; ++k) {
            const int i = ch * 8 + k;
            const float t0 = __shfl(wlo, 2 * i + p, 64);
            const float t1 = __shfl(whi, 2 * i + p, 64);
            const float wt = hiHalf ? t1 : t0;
            const float4 fv = *(const float4*)(fbase + (size_t)i * D_);
            acc.x += wt * fv.x;
            acc.y += wt * fv.y;
            acc.z += wt * fv.z;
            acc.w += wt * fv.w;
        }
    }

    *(float4*)(out + (size_t)bs * D_ + colbase) = acc;
}

extern "C" void kernel_launch(void* const* d_in, const int* in_sizes, int n_in,
                              void* d_out, int out_size, void* d_ws, size_t ws_size,
                              hipStream_t stream) {
    const float* feat   = (const float*)d_in[0];   // features f32 [B,T,D]
    const int*   begins = (const int*)d_in[1];     // int32 [B,S]
    const int*   ends   = (const int*)d_in[2];     // int32 [B,S]
    const float* kw     = (const float*)d_in[3];   // key_w f32 [H,D]
    const float* kb     = (const float*)d_in[4];   // key_b f32 [H]
    float*       out    = (float*)d_out;           // f32 [B*S, D]
    float* logits = (float*)d_ws;                  // 16384*8*4 = 512 KB scratch

    logits_kernel<<<(B_ * T_) / 32, 256, 0, stream>>>(feat, kw, kb, logits);
    pool_kernel<<<B_ * S_, 256, 0, stream>>>(feat, begins, ends, logits, out);
}